// Round 11
// baseline (59.911 us; speedup 1.0000x reference)
//
#include <hip/hip_runtime.h>

#define N_TOT  524288
#define NN1    524289
#define PP     8
#define AA     65536
#define SEGLEN 64
#define NSEG   8193      /* ceil(NN1/64) */
#define CHUNK  64        /* segments per chunk (full wave) */
#define NCHK   129       /* ceil(NSEG/64) */
#define NE     (NCHK*4)  /* 516 link slots */

/* workspace offsets, in floats (all float4-aligned) */
#define OFF_NT    0           /* float4[NN1] = 2097156 floats */
#define OFF_KINV  2097156     /* N_TOT ints */
#define OFF_L1G   2621444     /* NSEG*48 = 393264 */
#define OFF_L1E   3014708     /* NSEG*4 ints */
#define OFF_PREG  3047480     /* NSEG*48 */
#define OFF_PREE  3440744     /* NSEG*4 ints */
#define OFF_CLG   3473516     /* NE*12 = 6192 */
#define OFF_CLE   3479708     /* NE ints */
#define OFF_BCG   3480224     /* NE*12 = 6192 */

static __device__ __forceinline__ void set_ident(float* a){
  a[0]=1.f;a[1]=0.f;a[2]=0.f;a[3]=0.f;
  a[4]=0.f;a[5]=1.f;a[6]=0.f;a[7]=0.f;
  a[8]=0.f;a[9]=0.f;a[10]=1.f;a[11]=0.f;
}

/* O = A @ B (3x4 affine, row-major) */
static __device__ __forceinline__ void compose(const float* Aa, const float* B, float* O){
  #pragma unroll
  for(int r=0;r<3;r++){
    float a0=Aa[r*4+0],a1=Aa[r*4+1],a2=Aa[r*4+2],a3=Aa[r*4+3];
    O[r*4+0]=a0*B[0]+a1*B[4]+a2*B[8];
    O[r*4+1]=a0*B[1]+a1*B[5]+a2*B[9];
    O[r*4+2]=a0*B[2]+a1*B[6]+a2*B[10];
    O[r*4+3]=a0*B[3]+a1*B[7]+a2*B[11]+a3;
  }
}

static __device__ __forceinline__ void load12(const float4* b4, int idx, float* a){
  float4 x=b4[idx*3+0], y=b4[idx*3+1], z=b4[idx*3+2];
  a[0]=x.x;a[1]=x.y;a[2]=x.z;a[3]=x.w;
  a[4]=y.x;a[5]=y.y;a[6]=y.z;a[7]=y.w;
  a[8]=z.x;a[9]=z.y;a[10]=z.z;a[11]=z.w;
}
static __device__ __forceinline__ void store12(float4* b4, int idx, const float* a){
  b4[idx*3+0]=make_float4(a[0],a[1],a[2],a[3]);
  b4[idx*3+1]=make_float4(a[4],a[5],a[6],a[7]);
  b4[idx*3+2]=make_float4(a[8],a[9],a[10],a[11]);
}

/* Wave-parallel doubling scan for one 64-node segment (proven r2-r10). */
static __device__ __forceinline__ void wave_scan(
    int w, int lane,
    const float* __restrict__ masked, const float4* __restrict__ base4,
    const int* __restrict__ parents,
    float G[12], int& pk)
{
  int i0 = w*SEGLEN;
  int i = i0 + lane;
  if(i == 0 || i >= NN1){
    set_ident(G); pk = 0xFF;
  } else {
    float4 b = base4[i];
    float phi = masked[i];
    float sp,cp,st,ct;
    __sincosf(phi,&sp,&cp);
    __sincosf(b.y,&st,&ct);
    float dd = b.z;
    G[0]=cp*ct; G[1]=-sp; G[2]=cp*st; G[3]=dd*G[0];
    G[4]=sp*ct; G[5]=cp;  G[6]=sp*st; G[7]=dd*G[4];
    G[8]=-st;   G[9]=0.f; G[10]=ct;   G[11]=dd*G[8];
    int rel = parents[i] - i0;
    pk = (rel >= 0) ? rel : (((rel+4)<<8) | 0xFF);
  }
  #pragma unroll
  for(int step=0; step<6; ++step){
    int ptr = pk & 0xFF;
    bool act = (ptr != 0xFF);
    int src = act ? ptr : lane;
    float g2[12];
    #pragma unroll
    for(int q=0;q<12;q++) g2[q] = __shfl(G[q], src, 64);
    int pk2 = __shfl(pk, src, 64);
    float ng[12];
    compose(g2, G, ng);
    #pragma unroll
    for(int q=0;q<12;q++) G[q] = act ? ng[q] : G[q];
    pk = act ? pk2 : pk;
  }
}

/* fk1: level-0 wave scans -> NT (t_rel, tag), kinInv scatter, segment links;
   zero d_out. */
__global__ __launch_bounds__(1024) void fk1(
    const float* __restrict__ masked, const float4* __restrict__ base4,
    const int* __restrict__ parents, const int* __restrict__ kin,
    float4* __restrict__ L1G, int* __restrict__ L1E,
    float4* __restrict__ NT, int* __restrict__ kinInv,
    float* __restrict__ out)
{
  if(blockIdx.x==0 && threadIdx.x < PP) out[threadIdx.x] = 0.f;
  int w = blockIdx.x*16 + (threadIdx.x>>6);
  if(w >= NSEG) return;
  int lane = threadIdx.x & 63;
  float G[12]; int pk;
  wave_scan(w, lane, masked, base4, parents, G, pk);
  int i = w*SEGLEN + lane;
  int tag = (pk>>8)&3;
  if(i < NN1){
    NT[i] = make_float4(G[3], G[7], G[11], __int_as_float(tag));
    if(i > 0) kinInv[kin[i-1]] = i;
  }
  if(lane >= 60){
    int j = lane - 60;
    store12(L1G, w*4+j, G);
    L1E[w*4+j] = tag;
  }
}

/* fk2: one wave per chunk of 64 segments; Hillis-Steele doubling over the
   window monoid (4 transforms + 4 entry tags per lane). Full-wave version
   of the r10-proven kernel (CHUNK 33 -> 64). */
__global__ __launch_bounds__(64) void fk2(
    const float4* __restrict__ L1G, const int* __restrict__ L1E,
    float4* __restrict__ PREG, int* __restrict__ PREE,
    float4* __restrict__ CLG, int* __restrict__ CLE)
{
  int g = blockIdx.x;           /* chunk id 0..NCHK-1 */
  int j = threadIdx.x;          /* lane = local segment index */
  int s0 = g*CHUNK;
  int ns = min(CHUNK, NSEG - s0);
  int sj = s0 + min(j, ns-1);   /* clamped load index */

  float A[4][12]; int at[4];
  #pragma unroll
  for(int t=0;t<4;t++){
    load12(L1G, sj*4+t, A[t]);
    at[t] = L1E[sj*4+t];
  }
  if(j >= ns){
    #pragma unroll
    for(int t=0;t<4;t++){ set_ident(A[t]); at[t]=t; }
  }

  #pragma unroll
  for(int step=0; step<6; ++step){
    int d = 1<<step;
    int src = (j >= d) ? (j - d) : j;
    float f[4][12]; int ft[4];
    #pragma unroll
    for(int t=0;t<4;t++){
      #pragma unroll
      for(int q=0;q<12;q++) f[t][q] = __shfl(A[t][q], src, 64);
      ft[t] = __shfl(at[t], src, 64);
    }
    bool act = (j >= d) && (j < ns);
    float nA[4][12]; int nt[4];
    #pragma unroll
    for(int t=0;t<4;t++){
      int tt = at[t];
      float sel[12];
      #pragma unroll
      for(int q=0;q<12;q++){
        float v01 = (tt&1) ? f[1][q] : f[0][q];
        float v23 = (tt&1) ? f[3][q] : f[2][q];
        sel[q] = (tt&2) ? v23 : v01;
      }
      compose(sel, A[t], nA[t]);
      int t01 = (tt&1) ? ft[1] : ft[0];
      int t23 = (tt&1) ? ft[3] : ft[2];
      nt[t] = (tt&2) ? t23 : t01;
    }
    #pragma unroll
    for(int t=0;t<4;t++){
      #pragma unroll
      for(int q=0;q<12;q++) A[t][q] = act ? nA[t][q] : A[t][q];
      at[t] = act ? nt[t] : at[t];
    }
  }

  /* writes: exclusive prefix = scanned value of lane j -> segment j+1 */
  if(j == 0){
    float I[12]; set_ident(I);
    #pragma unroll
    for(int t=0;t<4;t++){
      store12(PREG, s0*4+t, I);
      PREE[s0*4+t] = t;
    }
  }
  if(j < ns-1){
    #pragma unroll
    for(int t=0;t<4;t++){
      store12(PREG, (s0+j+1)*4+t, A[t]);
      PREE[(s0+j+1)*4+t] = at[t];
    }
  }
  if(j == ns-1){
    #pragma unroll
    for(int t=0;t<4;t++){
      store12(CLG, g*4+t, A[t]);
      CLE[g*4+t] = at[t];
    }
  }
}

/* fk3: single 1024-thread block — float4-LDS doubling over NE chunk links
   (proven r5-r10; now 516 slots, 8 steps). */
__global__ __launch_bounds__(1024) void fk3(
    const float4* __restrict__ CLG, const int* __restrict__ CLE,
    float4* __restrict__ BCG)
{
  __shared__ float Lg[NE*12];
  __shared__ int   Le[NE];
  float4* Lg4 = (float4*)Lg;
  int tid = threadIdx.x;
  if(tid < NE){
    float a[12]; load12(CLG, tid, a);
    Lg4[tid*3+0]=make_float4(a[0],a[1],a[2],a[3]);
    Lg4[tid*3+1]=make_float4(a[4],a[5],a[6],a[7]);
    Lg4[tid*3+2]=make_float4(a[8],a[9],a[10],a[11]);
    Le[tid]=CLE[tid];
  }
  __syncthreads();
  for(int d=1; d<NCHK; d<<=1){
    float ng[12]; int ne2=0;
    bool doit = (tid<NE) && ((tid>>2)>=d);
    if(doit){
      int myE = Le[tid];
      int pe = ((tid>>2)-d)*4 + myE;
      float own[12], pg[12];
      load12(Lg4, tid, own);
      load12(Lg4, pe, pg);
      compose(pg, own, ng);
      ne2 = Le[pe];
    }
    __syncthreads();
    if(doit){
      Lg4[tid*3+0]=make_float4(ng[0],ng[1],ng[2],ng[3]);
      Lg4[tid*3+1]=make_float4(ng[4],ng[5],ng[6],ng[7]);
      Lg4[tid*3+2]=make_float4(ng[8],ng[9],ng[10],ng[11]);
      Le[tid]=ne2;
    }
    __syncthreads();
  }
  if(tid < NE){
    float b[12];
    if((tid>>2)==0){ set_ident(b); }
    else { load12(Lg4, tid-4, b); }
    store12(BCG, tid, b);
  }
}

/* fk45: fused position + bond energy. Block b covers 1024 output positions
   [b*1023, b*1023+1023] (overlap 1), computes each position by gathering
   its node's (t_rel, tag) + boundary transforms, stages positions in LDS,
   then reduces 1023 bond energies (two-pose split; a block spans <= 2 poses). */
__global__ __launch_bounds__(1024) void fk45(
    const int* __restrict__ kinInv, const float4* __restrict__ NT,
    const float4* __restrict__ PREG, const int* __restrict__ PREE,
    const float4* __restrict__ BCG, const float* __restrict__ bw,
    float* __restrict__ out)
{
  __shared__ float spos[1024*3];
  __shared__ float red0[16], red1[16];
  int tid = threadIdx.x;
  int base = blockIdx.x * 1023;
  int r = base + tid;
  if(r < N_TOT){
    int i = kinInv[r];
    float4 nt = NT[i];
    int tag = __float_as_int(nt.w) & 3;
    int w = i >> 6;
    int c = w >> 6;               /* CHUNK = 64 */
    int e = PREE[w*4+tag];
    float bg[12], pg[12], A[12];
    load12(BCG, c*4+e, bg);
    load12(PREG, w*4+tag, pg);
    compose(bg, pg, A);
    spos[tid*3+0] = A[0]*nt.x + A[1]*nt.y + A[2]*nt.z  + A[3];
    spos[tid*3+1] = A[4]*nt.x + A[5]*nt.y + A[6]*nt.z  + A[7];
    spos[tid*3+2] = A[8]*nt.x + A[9]*nt.y + A[10]*nt.z + A[11];
  }
  __syncthreads();
  int pFirst = base >> 16;        /* AA = 65536 */
  float s0 = 0.f, s1 = 0.f;
  if(tid < 1023 && r < N_TOT-1 && ((r & (AA-1)) != AA-1)){
    float dx = spos[(tid+1)*3+0]-spos[tid*3+0];
    float dy = spos[(tid+1)*3+1]-spos[tid*3+1];
    float dz = spos[(tid+1)*3+2]-spos[tid*3+2];
    int p = r >> 16;
    int a = r & (AA-1);
    float ev = bw[p*(AA-1)+a]*(dx*dx+dy*dy+dz*dz);
    if(p == pFirst) s0 = ev; else s1 = ev;
  }
  #pragma unroll
  for(int off=32; off>0; off>>=1){
    s0 += __shfl_down(s0, off, 64);
    s1 += __shfl_down(s1, off, 64);
  }
  int lane = tid & 63, wid = tid >> 6;
  if(lane == 0){ red0[wid] = s0; red1[wid] = s1; }
  __syncthreads();
  if(tid == 0){
    float t0 = 0.f, t1 = 0.f;
    #pragma unroll
    for(int q=0;q<16;q++){ t0 += red0[q]; t1 += red1[q]; }
    atomicAdd(&out[pFirst], t0);
    if(pFirst+1 < PP) atomicAdd(&out[pFirst+1], t1);
  }
}

extern "C" void kernel_launch(void* const* d_in, const int* in_sizes, int n_in,
                              void* d_out, int out_size, void* d_ws, size_t ws_size,
                              hipStream_t stream)
{
  const float*  masked  = (const float*)d_in[0];
  const float4* base4   = (const float4*)d_in[1];
  /* d_in[2] pose_coords unused: kin_id is a full permutation */
  const float*  bw      = (const float*)d_in[3];
  const int*    parents = (const int*)d_in[4];
  const int*    kin     = (const int*)d_in[5];

  float* ws = (float*)d_ws;
  float4* NT   = (float4*)(ws + OFF_NT);
  int*    kinInv = (int*)(ws + OFF_KINV);
  float4* L1G  = (float4*)(ws + OFF_L1G);
  int*    L1E  = (int*)(ws + OFF_L1E);
  float4* PREG = (float4*)(ws + OFF_PREG);
  int*    PREE = (int*)(ws + OFF_PREE);
  float4* CLG  = (float4*)(ws + OFF_CLG);
  int*    CLE  = (int*)(ws + OFF_CLE);
  float4* BCG  = (float4*)(ws + OFF_BCG);
  float*  out  = (float*)d_out;

  int nblk = (NSEG + 15) / 16;        /* 513 blocks of 1024 threads */
  int nblk45 = (N_TOT - 1 + 1022) / 1023;  /* 513 blocks */
  fk1<<<nblk, 1024, 0, stream>>>(masked, base4, parents, kin, L1G, L1E, NT, kinInv, out);
  fk2<<<NCHK, 64, 0, stream>>>(L1G, L1E, PREG, PREE, CLG, CLE);
  fk3<<<1, 1024, 0, stream>>>(CLG, CLE, BCG);
  fk45<<<nblk45, 1024, 0, stream>>>(kinInv, NT, PREG, PREE, BCG, bw, out);
}

// Round 12
// 48.292 us; speedup vs baseline: 1.2406x; 1.2406x over previous
//
#include <hip/hip_runtime.h>

#define N_TOT  524288
#define NN1    524289
#define PP     8
#define AA     65536
#define SEGLEN 64
#define NSEG   8193      /* ceil(NN1/64) */
#define CHUNK  64        /* segments per chunk (full wave) */
#define NCHK   129       /* ceil(NSEG/64) */
#define NE     (NCHK*4)  /* 516 link slots */

/* workspace offsets, in floats (all float4-aligned) */
#define OFF_COORDS 0          /* float4[524288] = 2097152 floats */
#define OFF_NT   2097152      /* float4[NN1]    = 2097156 floats */
#define OFF_L1G  4194308      /* NSEG*48 = 393264 */
#define OFF_L1E  4587572      /* NSEG*4 ints */
#define OFF_PREG 4620344      /* NSEG*48 */
#define OFF_PREE 5013608      /* NSEG*4 ints */
#define OFF_BCG  5046380      /* NE*12 = 6192 */
#define OFF_CLG  5052572      /* NE*12 = 6192 */
#define OFF_CLE  5058764      /* NE ints */

static __device__ __forceinline__ void set_ident(float* a){
  a[0]=1.f;a[1]=0.f;a[2]=0.f;a[3]=0.f;
  a[4]=0.f;a[5]=1.f;a[6]=0.f;a[7]=0.f;
  a[8]=0.f;a[9]=0.f;a[10]=1.f;a[11]=0.f;
}

/* O = A @ B (3x4 affine, row-major) */
static __device__ __forceinline__ void compose(const float* Aa, const float* B, float* O){
  #pragma unroll
  for(int r=0;r<3;r++){
    float a0=Aa[r*4+0],a1=Aa[r*4+1],a2=Aa[r*4+2],a3=Aa[r*4+3];
    O[r*4+0]=a0*B[0]+a1*B[4]+a2*B[8];
    O[r*4+1]=a0*B[1]+a1*B[5]+a2*B[9];
    O[r*4+2]=a0*B[2]+a1*B[6]+a2*B[10];
    O[r*4+3]=a0*B[3]+a1*B[7]+a2*B[11]+a3;
  }
}

static __device__ __forceinline__ void load12(const float4* b4, int idx, float* a){
  float4 x=b4[idx*3+0], y=b4[idx*3+1], z=b4[idx*3+2];
  a[0]=x.x;a[1]=x.y;a[2]=x.z;a[3]=x.w;
  a[4]=y.x;a[5]=y.y;a[6]=y.z;a[7]=y.w;
  a[8]=z.x;a[9]=z.y;a[10]=z.z;a[11]=z.w;
}
static __device__ __forceinline__ void store12(float4* b4, int idx, const float* a){
  b4[idx*3+0]=make_float4(a[0],a[1],a[2],a[3]);
  b4[idx*3+1]=make_float4(a[4],a[5],a[6],a[7]);
  b4[idx*3+2]=make_float4(a[8],a[9],a[10],a[11]);
}

/* Wave-parallel doubling scan for one 64-node segment (proven r2-r11). */
static __device__ __forceinline__ void wave_scan(
    int w, int lane,
    const float* __restrict__ masked, const float4* __restrict__ base4,
    const int* __restrict__ parents,
    float G[12], int& pk)
{
  int i0 = w*SEGLEN;
  int i = i0 + lane;
  if(i == 0 || i >= NN1){
    set_ident(G); pk = 0xFF;
  } else {
    float4 b = base4[i];
    float phi = masked[i];
    float sp,cp,st,ct;
    __sincosf(phi,&sp,&cp);
    __sincosf(b.y,&st,&ct);
    float dd = b.z;
    G[0]=cp*ct; G[1]=-sp; G[2]=cp*st; G[3]=dd*G[0];
    G[4]=sp*ct; G[5]=cp;  G[6]=sp*st; G[7]=dd*G[4];
    G[8]=-st;   G[9]=0.f; G[10]=ct;   G[11]=dd*G[8];
    int rel = parents[i] - i0;
    pk = (rel >= 0) ? rel : (((rel+4)<<8) | 0xFF);
  }
  #pragma unroll
  for(int step=0; step<6; ++step){
    int ptr = pk & 0xFF;
    bool act = (ptr != 0xFF);
    int src = act ? ptr : lane;
    float g2[12];
    #pragma unroll
    for(int q=0;q<12;q++) g2[q] = __shfl(G[q], src, 64);
    int pk2 = __shfl(pk, src, 64);
    float ng[12];
    compose(g2, G, ng);
    #pragma unroll
    for(int q=0;q<12;q++) G[q] = act ? ng[q] : G[q];
    pk = act ? pk2 : pk;
  }
}

/* fk1: level-0 wave scans -> NT (t_rel, tag), segment links; zero d_out. */
__global__ __launch_bounds__(1024) void fk1(
    const float* __restrict__ masked, const float4* __restrict__ base4,
    const int* __restrict__ parents,
    float4* __restrict__ L1G, int* __restrict__ L1E,
    float4* __restrict__ NT, float* __restrict__ out)
{
  if(blockIdx.x==0 && threadIdx.x < PP) out[threadIdx.x] = 0.f;
  int w = blockIdx.x*16 + (threadIdx.x>>6);
  if(w >= NSEG) return;
  int lane = threadIdx.x & 63;
  float G[12]; int pk;
  wave_scan(w, lane, masked, base4, parents, G, pk);
  int i = w*SEGLEN + lane;
  int tag = (pk>>8)&3;
  if(i < NN1){
    NT[i] = make_float4(G[3], G[7], G[11], __int_as_float(tag));
  }
  if(lane >= 60){
    int j = lane - 60;
    store12(L1G, w*4+j, G);
    L1E[w*4+j] = tag;
  }
}

/* fk2: one wave per chunk of 64 segments; Hillis-Steele doubling over the
   window monoid (4 transforms + 4 entry tags per lane). Proven r10/r11. */
__global__ __launch_bounds__(64) void fk2(
    const float4* __restrict__ L1G, const int* __restrict__ L1E,
    float4* __restrict__ PREG, int* __restrict__ PREE,
    float4* __restrict__ CLG, int* __restrict__ CLE)
{
  int g = blockIdx.x;           /* chunk id 0..NCHK-1 */
  int j = threadIdx.x;          /* lane = local segment index */
  int s0 = g*CHUNK;
  int ns = min(CHUNK, NSEG - s0);
  int sj = s0 + min(j, ns-1);   /* clamped load index */

  float A[4][12]; int at[4];
  #pragma unroll
  for(int t=0;t<4;t++){
    load12(L1G, sj*4+t, A[t]);
    at[t] = L1E[sj*4+t];
  }
  if(j >= ns){
    #pragma unroll
    for(int t=0;t<4;t++){ set_ident(A[t]); at[t]=t; }
  }

  #pragma unroll
  for(int step=0; step<6; ++step){
    int d = 1<<step;
    int src = (j >= d) ? (j - d) : j;
    float f[4][12]; int ft[4];
    #pragma unroll
    for(int t=0;t<4;t++){
      #pragma unroll
      for(int q=0;q<12;q++) f[t][q] = __shfl(A[t][q], src, 64);
      ft[t] = __shfl(at[t], src, 64);
    }
    bool act = (j >= d) && (j < ns);
    float nA[4][12]; int nt[4];
    #pragma unroll
    for(int t=0;t<4;t++){
      int tt = at[t];
      float sel[12];
      #pragma unroll
      for(int q=0;q<12;q++){
        float v01 = (tt&1) ? f[1][q] : f[0][q];
        float v23 = (tt&1) ? f[3][q] : f[2][q];
        sel[q] = (tt&2) ? v23 : v01;
      }
      compose(sel, A[t], nA[t]);
      int t01 = (tt&1) ? ft[1] : ft[0];
      int t23 = (tt&1) ? ft[3] : ft[2];
      nt[t] = (tt&2) ? t23 : t01;
    }
    #pragma unroll
    for(int t=0;t<4;t++){
      #pragma unroll
      for(int q=0;q<12;q++) A[t][q] = act ? nA[t][q] : A[t][q];
      at[t] = act ? nt[t] : at[t];
    }
  }

  /* writes: exclusive prefix = scanned value of lane j -> segment j+1 */
  if(j == 0){
    float I[12]; set_ident(I);
    #pragma unroll
    for(int t=0;t<4;t++){
      store12(PREG, s0*4+t, I);
      PREE[s0*4+t] = t;
    }
  }
  if(j < ns-1){
    #pragma unroll
    for(int t=0;t<4;t++){
      store12(PREG, (s0+j+1)*4+t, A[t]);
      PREE[(s0+j+1)*4+t] = at[t];
    }
  }
  if(j == ns-1){
    #pragma unroll
    for(int t=0;t<4;t++){
      store12(CLG, g*4+t, A[t]);
      CLE[g*4+t] = at[t];
    }
  }
}

/* fk3: single 1024-thread block — float4-LDS doubling over NE chunk links
   (proven r5-r11; 516 slots, 8 steps). */
__global__ __launch_bounds__(1024) void fk3(
    const float4* __restrict__ CLG, const int* __restrict__ CLE,
    float4* __restrict__ BCG)
{
  __shared__ float Lg[NE*12];
  __shared__ int   Le[NE];
  float4* Lg4 = (float4*)Lg;
  int tid = threadIdx.x;
  if(tid < NE){
    float a[12]; load12(CLG, tid, a);
    Lg4[tid*3+0]=make_float4(a[0],a[1],a[2],a[3]);
    Lg4[tid*3+1]=make_float4(a[4],a[5],a[6],a[7]);
    Lg4[tid*3+2]=make_float4(a[8],a[9],a[10],a[11]);
    Le[tid]=CLE[tid];
  }
  __syncthreads();
  for(int d=1; d<NCHK; d<<=1){
    float ng[12]; int ne2=0;
    bool doit = (tid<NE) && ((tid>>2)>=d);
    if(doit){
      int myE = Le[tid];
      int pe = ((tid>>2)-d)*4 + myE;
      float own[12], pg[12];
      load12(Lg4, tid, own);
      load12(Lg4, pe, pg);
      compose(pg, own, ng);
      ne2 = Le[pe];
    }
    __syncthreads();
    if(doit){
      Lg4[tid*3+0]=make_float4(ng[0],ng[1],ng[2],ng[3]);
      Lg4[tid*3+1]=make_float4(ng[4],ng[5],ng[6],ng[7]);
      Lg4[tid*3+2]=make_float4(ng[8],ng[9],ng[10],ng[11]);
      Le[tid]=ne2;
    }
    __syncthreads();
  }
  if(tid < NE){
    float b[12];
    if((tid>>2)==0){ set_ident(b); }
    else { load12(Lg4, tid-4, b); }
    store12(BCG, tid, b);
  }
}

/* fk4: apply absolute boundary to NT; scatter via kin_id (proven r10:
   wave-uniform PREG/BCG loads + coalesced NT read + scatter write). */
__global__ __launch_bounds__(1024) void fk4(
    const int* __restrict__ kin, const float4* __restrict__ NT,
    const float4* __restrict__ PREG, const int* __restrict__ PREE,
    const float4* __restrict__ BCG,
    float4* __restrict__ coords)
{
  int w = blockIdx.x*16 + (threadIdx.x>>6);
  if(w >= NSEG) return;
  int lane = threadIdx.x & 63;
  int i = w*SEGLEN + lane;
  if(i == 0 || i >= NN1) return;
  float4 nt = NT[i];
  int tag = __float_as_int(nt.w) & 3;
  int c = w >> 6;                /* CHUNK = 64 */
  int e = PREE[w*4+tag];
  float bg[12], pg[12], A[12];
  load12(BCG, c*4+e, bg);
  load12(PREG, w*4+tag, pg);
  compose(bg, pg, A);
  float x = A[0]*nt.x + A[1]*nt.y + A[2]*nt.z  + A[3];
  float y = A[4]*nt.x + A[5]*nt.y + A[6]*nt.z  + A[7];
  float z = A[8]*nt.x + A[9]*nt.y + A[10]*nt.z + A[11];
  coords[kin[i-1]] = make_float4(x, y, z, 0.f);
}

/* fk5: bond energy; 32 blocks/pose, shfl+LDS reduce, atomicAdd (proven r2-r10) */
__global__ void fk5(const float4* __restrict__ coords, const float* __restrict__ bw,
                    float* __restrict__ out)
{
  int p = blockIdx.x >> 5;
  int sub = blockIdx.x & 31;
  int a0 = sub * 2048;
  int aend = min(a0 + 2048, AA - 1);
  float sum = 0.f;
  for(int a = a0 + (int)threadIdx.x; a < aend; a += 256){
    int r = p*AA + a;
    float4 c0 = coords[r], c1 = coords[r+1];
    float dx = c1.x-c0.x, dy = c1.y-c0.y, dz = c1.z-c0.z;
    sum += bw[p*(AA-1)+a]*(dx*dx+dy*dy+dz*dz);
  }
  #pragma unroll
  for(int off=32;off>0;off>>=1) sum += __shfl_down(sum, off, 64);
  __shared__ float red[4];
  int lane = threadIdx.x & 63, wid = threadIdx.x >> 6;
  if(lane==0) red[wid]=sum;
  __syncthreads();
  if(threadIdx.x==0){
    float tot = red[0]+red[1]+red[2]+red[3];
    atomicAdd(&out[p], tot);
  }
}

extern "C" void kernel_launch(void* const* d_in, const int* in_sizes, int n_in,
                              void* d_out, int out_size, void* d_ws, size_t ws_size,
                              hipStream_t stream)
{
  const float*  masked  = (const float*)d_in[0];
  const float4* base4   = (const float4*)d_in[1];
  /* d_in[2] pose_coords unused: kin_id is a full permutation */
  const float*  bw      = (const float*)d_in[3];
  const int*    parents = (const int*)d_in[4];
  const int*    kin     = (const int*)d_in[5];

  float* ws = (float*)d_ws;
  float4* coords = (float4*)(ws + OFF_COORDS);
  float4* NT   = (float4*)(ws + OFF_NT);
  float4* L1G  = (float4*)(ws + OFF_L1G);
  int*    L1E  = (int*)(ws + OFF_L1E);
  float4* PREG = (float4*)(ws + OFF_PREG);
  int*    PREE = (int*)(ws + OFF_PREE);
  float4* BCG  = (float4*)(ws + OFF_BCG);
  float4* CLG  = (float4*)(ws + OFF_CLG);
  int*    CLE  = (int*)(ws + OFF_CLE);
  float*  out  = (float*)d_out;

  int nblk = (NSEG + 15) / 16;   /* 513 blocks of 1024 threads (16 waves) */
  fk1<<<nblk, 1024, 0, stream>>>(masked, base4, parents, L1G, L1E, NT, out);
  fk2<<<NCHK, 64, 0, stream>>>(L1G, L1E, PREG, PREE, CLG, CLE);
  fk3<<<1, 1024, 0, stream>>>(CLG, CLE, BCG);
  fk4<<<nblk, 1024, 0, stream>>>(kin, NT, PREG, PREE, BCG, coords);
  fk5<<<PP*32, 256, 0, stream>>>(coords, bw, out);
}

// Round 13
// 47.680 us; speedup vs baseline: 1.2565x; 1.0128x over previous
//
#include <hip/hip_runtime.h>

#define N_TOT  524288
#define NN1    524289
#define PP     8
#define AA     65536
#define SEGLEN 64
#define NSEG   8193      /* ceil(NN1/64) */
#define CHUNK  64        /* segments per chunk (full wave) */
#define NCHK   129       /* ceil(NSEG/64) */
#define NE     (NCHK*4)  /* 516 link slots */

/* workspace offsets, in floats (all float4-aligned) */
#define OFF_COORDS 0          /* float4[524288] = 2097152 floats */
#define OFF_NT   2097152      /* float4[NN1]    = 2097156 floats */
#define OFF_L1G  4194308      /* NSEG*48 = 393264 */
#define OFF_L1E  4587572      /* NSEG*4 ints */
#define OFF_PREG 4620344      /* NSEG*48 */
#define OFF_PREE 5013608      /* NSEG*4 ints */
#define OFF_CLG  5046380      /* NE*12 = 6192 */
#define OFF_CLE  5052572      /* NE ints */

static __device__ __forceinline__ void set_ident(float* a){
  a[0]=1.f;a[1]=0.f;a[2]=0.f;a[3]=0.f;
  a[4]=0.f;a[5]=1.f;a[6]=0.f;a[7]=0.f;
  a[8]=0.f;a[9]=0.f;a[10]=1.f;a[11]=0.f;
}

/* O = A @ B (3x4 affine, row-major) */
static __device__ __forceinline__ void compose(const float* Aa, const float* B, float* O){
  #pragma unroll
  for(int r=0;r<3;r++){
    float a0=Aa[r*4+0],a1=Aa[r*4+1],a2=Aa[r*4+2],a3=Aa[r*4+3];
    O[r*4+0]=a0*B[0]+a1*B[4]+a2*B[8];
    O[r*4+1]=a0*B[1]+a1*B[5]+a2*B[9];
    O[r*4+2]=a0*B[2]+a1*B[6]+a2*B[10];
    O[r*4+3]=a0*B[3]+a1*B[7]+a2*B[11]+a3;
  }
}

static __device__ __forceinline__ void load12(const float4* b4, int idx, float* a){
  float4 x=b4[idx*3+0], y=b4[idx*3+1], z=b4[idx*3+2];
  a[0]=x.x;a[1]=x.y;a[2]=x.z;a[3]=x.w;
  a[4]=y.x;a[5]=y.y;a[6]=y.z;a[7]=y.w;
  a[8]=z.x;a[9]=z.y;a[10]=z.z;a[11]=z.w;
}
static __device__ __forceinline__ void store12(float4* b4, int idx, const float* a){
  b4[idx*3+0]=make_float4(a[0],a[1],a[2],a[3]);
  b4[idx*3+1]=make_float4(a[4],a[5],a[6],a[7]);
  b4[idx*3+2]=make_float4(a[8],a[9],a[10],a[11]);
}

/* Wave-parallel doubling scan for one 64-node segment (proven r2-r12). */
static __device__ __forceinline__ void wave_scan(
    int w, int lane,
    const float* __restrict__ masked, const float4* __restrict__ base4,
    const int* __restrict__ parents,
    float G[12], int& pk)
{
  int i0 = w*SEGLEN;
  int i = i0 + lane;
  if(i == 0 || i >= NN1){
    set_ident(G); pk = 0xFF;
  } else {
    float4 b = base4[i];
    float phi = masked[i];
    float sp,cp,st,ct;
    __sincosf(phi,&sp,&cp);
    __sincosf(b.y,&st,&ct);
    float dd = b.z;
    G[0]=cp*ct; G[1]=-sp; G[2]=cp*st; G[3]=dd*G[0];
    G[4]=sp*ct; G[5]=cp;  G[6]=sp*st; G[7]=dd*G[4];
    G[8]=-st;   G[9]=0.f; G[10]=ct;   G[11]=dd*G[8];
    int rel = parents[i] - i0;
    pk = (rel >= 0) ? rel : (((rel+4)<<8) | 0xFF);
  }
  #pragma unroll
  for(int step=0; step<6; ++step){
    int ptr = pk & 0xFF;
    bool act = (ptr != 0xFF);
    int src = act ? ptr : lane;
    float g2[12];
    #pragma unroll
    for(int q=0;q<12;q++) g2[q] = __shfl(G[q], src, 64);
    int pk2 = __shfl(pk, src, 64);
    float ng[12];
    compose(g2, G, ng);
    #pragma unroll
    for(int q=0;q<12;q++) G[q] = act ? ng[q] : G[q];
    pk = act ? pk2 : pk;
  }
}

/* fk1: level-0 wave scans -> NT (t_rel, tag), segment links; zero d_out. */
__global__ __launch_bounds__(1024) void fk1(
    const float* __restrict__ masked, const float4* __restrict__ base4,
    const int* __restrict__ parents,
    float4* __restrict__ L1G, int* __restrict__ L1E,
    float4* __restrict__ NT, float* __restrict__ out)
{
  if(blockIdx.x==0 && threadIdx.x < PP) out[threadIdx.x] = 0.f;
  int w = blockIdx.x*16 + (threadIdx.x>>6);
  if(w >= NSEG) return;
  int lane = threadIdx.x & 63;
  float G[12]; int pk;
  wave_scan(w, lane, masked, base4, parents, G, pk);
  int i = w*SEGLEN + lane;
  int tag = (pk>>8)&3;
  if(i < NN1){
    NT[i] = make_float4(G[3], G[7], G[11], __int_as_float(tag));
  }
  if(lane >= 60){
    int j = lane - 60;
    store12(L1G, w*4+j, G);
    L1E[w*4+j] = tag;
  }
}

/* fk2: one wave per chunk of 64 segments; Hillis-Steele doubling over the
   window monoid (4 transforms + 4 entry tags per lane). Proven r10-r12. */
__global__ __launch_bounds__(64) void fk2(
    const float4* __restrict__ L1G, const int* __restrict__ L1E,
    float4* __restrict__ PREG, int* __restrict__ PREE,
    float4* __restrict__ CLG, int* __restrict__ CLE)
{
  int g = blockIdx.x;           /* chunk id 0..NCHK-1 */
  int j = threadIdx.x;          /* lane = local segment index */
  int s0 = g*CHUNK;
  int ns = min(CHUNK, NSEG - s0);
  int sj = s0 + min(j, ns-1);   /* clamped load index */

  float A[4][12]; int at[4];
  #pragma unroll
  for(int t=0;t<4;t++){
    load12(L1G, sj*4+t, A[t]);
    at[t] = L1E[sj*4+t];
  }
  if(j >= ns){
    #pragma unroll
    for(int t=0;t<4;t++){ set_ident(A[t]); at[t]=t; }
  }

  #pragma unroll
  for(int step=0; step<6; ++step){
    int d = 1<<step;
    int src = (j >= d) ? (j - d) : j;
    float f[4][12]; int ft[4];
    #pragma unroll
    for(int t=0;t<4;t++){
      #pragma unroll
      for(int q=0;q<12;q++) f[t][q] = __shfl(A[t][q], src, 64);
      ft[t] = __shfl(at[t], src, 64);
    }
    bool act = (j >= d) && (j < ns);
    float nA[4][12]; int nt[4];
    #pragma unroll
    for(int t=0;t<4;t++){
      int tt = at[t];
      float sel[12];
      #pragma unroll
      for(int q=0;q<12;q++){
        float v01 = (tt&1) ? f[1][q] : f[0][q];
        float v23 = (tt&1) ? f[3][q] : f[2][q];
        sel[q] = (tt&2) ? v23 : v01;
      }
      compose(sel, A[t], nA[t]);
      int t01 = (tt&1) ? ft[1] : ft[0];
      int t23 = (tt&1) ? ft[3] : ft[2];
      nt[t] = (tt&2) ? t23 : t01;
    }
    #pragma unroll
    for(int t=0;t<4;t++){
      #pragma unroll
      for(int q=0;q<12;q++) A[t][q] = act ? nA[t][q] : A[t][q];
      at[t] = act ? nt[t] : at[t];
    }
  }

  /* writes: exclusive prefix = scanned value of lane j -> segment j+1 */
  if(j == 0){
    float I[12]; set_ident(I);
    #pragma unroll
    for(int t=0;t<4;t++){
      store12(PREG, s0*4+t, I);
      PREE[s0*4+t] = t;
    }
  }
  if(j < ns-1){
    #pragma unroll
    for(int t=0;t<4;t++){
      store12(PREG, (s0+j+1)*4+t, A[t]);
      PREE[(s0+j+1)*4+t] = at[t];
    }
  }
  if(j == ns-1){
    #pragma unroll
    for(int t=0;t<4;t++){
      store12(CLG, g*4+t, A[t]);
      CLE[g*4+t] = at[t];
    }
  }
}

/* fk34: per-block redundant chunk-link doubling in LDS (replaces fk3's
   dispatch; CLG is 24.8 KB, L2-resident), then the proven fk4 apply+scatter.
   Doubling phase: all 1024 threads participate in syncs; apply phase has no
   syncs so the w-guard early-out is safe. */
__global__ __launch_bounds__(1024) void fk34(
    const int* __restrict__ kin, const float4* __restrict__ NT,
    const float4* __restrict__ PREG, const int* __restrict__ PREE,
    const float4* __restrict__ CLG, const int* __restrict__ CLE,
    float4* __restrict__ coords)
{
  __shared__ float Lg[NE*12];    /* 24.8 KB */
  __shared__ int   Le[NE];
  float4* Lg4 = (float4*)Lg;
  int tid = threadIdx.x;

  /* ---- doubling over chunk links (identical math to r12 fk3) ---- */
  if(tid < NE){
    float a[12]; load12(CLG, tid, a);
    Lg4[tid*3+0]=make_float4(a[0],a[1],a[2],a[3]);
    Lg4[tid*3+1]=make_float4(a[4],a[5],a[6],a[7]);
    Lg4[tid*3+2]=make_float4(a[8],a[9],a[10],a[11]);
    Le[tid]=CLE[tid];
  }
  __syncthreads();
  for(int d=1; d<NCHK; d<<=1){
    float ng[12]; int ne2=0;
    bool doit = (tid<NE) && ((tid>>2)>=d);
    if(doit){
      int myE = Le[tid];
      int pe = ((tid>>2)-d)*4 + myE;
      float own[12], pg[12];
      load12(Lg4, tid, own);
      load12(Lg4, pe, pg);
      compose(pg, own, ng);
      ne2 = Le[pe];
    }
    __syncthreads();
    if(doit){
      Lg4[tid*3+0]=make_float4(ng[0],ng[1],ng[2],ng[3]);
      Lg4[tid*3+1]=make_float4(ng[4],ng[5],ng[6],ng[7]);
      Lg4[tid*3+2]=make_float4(ng[8],ng[9],ng[10],ng[11]);
      Le[tid]=ne2;
    }
    __syncthreads();
  }

  /* ---- apply + scatter (proven fk4 body; bg from LDS) ---- */
  int w = blockIdx.x*16 + (tid>>6);
  if(w >= NSEG) return;
  int lane = tid & 63;
  int i = w*SEGLEN + lane;
  if(i == 0 || i >= NN1) return;
  float4 nt = NT[i];
  int tag = __float_as_int(nt.w) & 3;
  int c = w >> 6;                /* CHUNK = 64 */
  int e = PREE[w*4+tag];
  float bg[12], pg[12], A[12];
  if(c == 0){ set_ident(bg); }
  else { load12(Lg4, (c-1)*4+e, bg); }   /* BCG[c] == scan result of chunk c-1 */
  load12(PREG, w*4+tag, pg);
  compose(bg, pg, A);
  float x = A[0]*nt.x + A[1]*nt.y + A[2]*nt.z  + A[3];
  float y = A[4]*nt.x + A[5]*nt.y + A[6]*nt.z  + A[7];
  float z = A[8]*nt.x + A[9]*nt.y + A[10]*nt.z + A[11];
  coords[kin[i-1]] = make_float4(x, y, z, 0.f);
}

/* fk5: bond energy; 32 blocks/pose, shfl+LDS reduce, atomicAdd (proven r2-r12) */
__global__ void fk5(const float4* __restrict__ coords, const float* __restrict__ bw,
                    float* __restrict__ out)
{
  int p = blockIdx.x >> 5;
  int sub = blockIdx.x & 31;
  int a0 = sub * 2048;
  int aend = min(a0 + 2048, AA - 1);
  float sum = 0.f;
  for(int a = a0 + (int)threadIdx.x; a < aend; a += 256){
    int r = p*AA + a;
    float4 c0 = coords[r], c1 = coords[r+1];
    float dx = c1.x-c0.x, dy = c1.y-c0.y, dz = c1.z-c0.z;
    sum += bw[p*(AA-1)+a]*(dx*dx+dy*dy+dz*dz);
  }
  #pragma unroll
  for(int off=32;off>0;off>>=1) sum += __shfl_down(sum, off, 64);
  __shared__ float red[4];
  int lane = threadIdx.x & 63, wid = threadIdx.x >> 6;
  if(lane==0) red[wid]=sum;
  __syncthreads();
  if(threadIdx.x==0){
    float tot = red[0]+red[1]+red[2]+red[3];
    atomicAdd(&out[p], tot);
  }
}

extern "C" void kernel_launch(void* const* d_in, const int* in_sizes, int n_in,
                              void* d_out, int out_size, void* d_ws, size_t ws_size,
                              hipStream_t stream)
{
  const float*  masked  = (const float*)d_in[0];
  const float4* base4   = (const float4*)d_in[1];
  /* d_in[2] pose_coords unused: kin_id is a full permutation */
  const float*  bw      = (const float*)d_in[3];
  const int*    parents = (const int*)d_in[4];
  const int*    kin     = (const int*)d_in[5];

  float* ws = (float*)d_ws;
  float4* coords = (float4*)(ws + OFF_COORDS);
  float4* NT   = (float4*)(ws + OFF_NT);
  float4* L1G  = (float4*)(ws + OFF_L1G);
  int*    L1E  = (int*)(ws + OFF_L1E);
  float4* PREG = (float4*)(ws + OFF_PREG);
  int*    PREE = (int*)(ws + OFF_PREE);
  float4* CLG  = (float4*)(ws + OFF_CLG);
  int*    CLE  = (int*)(ws + OFF_CLE);
  float*  out  = (float*)d_out;

  int nblk = (NSEG + 15) / 16;   /* 513 blocks of 1024 threads (16 waves) */
  fk1<<<nblk, 1024, 0, stream>>>(masked, base4, parents, L1G, L1E, NT, out);
  fk2<<<NCHK, 64, 0, stream>>>(L1G, L1E, PREG, PREE, CLG, CLE);
  fk34<<<nblk, 1024, 0, stream>>>(kin, NT, PREG, PREE, CLG, CLE, coords);
  fk5<<<PP*32, 256, 0, stream>>>(coords, bw, out);
}